// Round 4
// baseline (1660.561 us; speedup 1.0000x reference)
//
#include <hip/hip_runtime.h>
#include <hip/hip_bf16.h>

#define Bq 64
#define Lq 256
#define Dq 350
#define HDq 128
#define Hq 256
#define G4 512   // 4*HD

typedef unsigned short u16;

__device__ __forceinline__ float bf2f(u16 u) {
    return __uint_as_float(((unsigned int)u) << 16);
}
__device__ __forceinline__ u16 f2bf(float f) {
    __hip_bfloat16 h = __float2bfloat16(f);
    return *(u16*)&h;
}
__device__ __forceinline__ float bflo(unsigned int u) {
    return __uint_as_float(u << 16);
}
__device__ __forceinline__ float bfhi(unsigned int u) {
    return __uint_as_float(u & 0xffff0000u);
}
// dtype-polymorphic float load: flag=1 -> buffer is f32, flag=0 -> bf16
__device__ __forceinline__ float loadf(const void* p, long i, int f32) {
    return f32 ? ((const float*)p)[i] : bf2f(((const u16*)p)[i]);
}
__device__ __forceinline__ float sigm(float x) {
    x = fminf(fmaxf(x, -30.f), 30.f);
    return 1.f / (1.f + __expf(-x));
}
__device__ __forceinline__ float tanh_(float x) {
    x = fminf(fmaxf(x, -15.f), 15.f);
    float e = __expf(2.f * x);
    return (e - 1.f) / (e + 1.f);
}
__device__ __forceinline__ float lse2(float x, float y) {
    float m = fmaxf(x, y);
    return m + logf(expf(x - m) + expf(y - m));
}

// ---------------------------------------------------------------------------
// Kernel 0: dtype detector. True bf16 data ~ N(0,0.1): no |x|>=2 when read as
// bf16. f32 data read as bf16: even-index u16s are mantissa garbage -> ~50%
// have |x|>=2 (or NaN). flag=1 means buffers are f32.
// ---------------------------------------------------------------------------
__global__ void detect_kernel(const void* we, int* flag) {
    if (threadIdx.x == 0 && blockIdx.x == 0) {
        const u16* p = (const u16*)we;
        int big = 0;
        for (int i = 0; i < 256; ++i) {
            float a = fabsf(bf2f(p[i]));
            if (!(a < 2.f)) big++;   // counts NaN too
        }
        *flag = (big > 16) ? 1 : 0;
    }
}

// ---------------------------------------------------------------------------
// Kernel 1: fused embedding-gather + input GEMM for ONE direction.
// xs[i,j] = sum_k x[i,k] * w_ih[j,k] + b_ih[j] + b_hh[j],  j in [0,512)
// Output xs is internal bf16.
// ---------------------------------------------------------------------------
#define BM 64
#define BN 64
#define BK 32
#define LDT 68  // padded LDS row stride (floats)

__global__ __launch_bounds__(256) void gemm_xs_kernel(
    const int* __restrict__ sents, const int* __restrict__ masks,
    const void* __restrict__ word_embed,
    const void* __restrict__ mask_embed,
    const void* __restrict__ w_ih,
    const void* __restrict__ b_ih,
    const void* __restrict__ b_hh,
    const int* __restrict__ flag,
    u16* __restrict__ xs)
{
    __shared__ __align__(16) float As[BK * LDT];
    __shared__ __align__(16) float Bs[BK * LDT];
    __shared__ int rowS[BM];
    __shared__ int rowM[BM];

    int f32 = *flag;
    int tid = threadIdx.x;
    int mBase = blockIdx.y * BM;
    int nBase = blockIdx.x * BN;   // nBase in [0, 512)
    if (tid < BM) {
        int i = mBase + tid;
        rowS[tid] = sents[i] * 300;
        rowM[tid] = masks[i] * 50;
    }
    int ty = tid >> 4, tx = tid & 15;
    float acc[4][4] = {};
    __syncthreads();

    for (int kt = 0; kt < 11; ++kt) {
        int k0 = kt * BK;
#pragma unroll
        for (int e = 0; e < 8; ++e) {
            int idx = e * 256 + tid;
            int m = idx >> 5, kk = idx & 31;
            int gk = k0 + kk;
            float av = 0.f;
            if (gk < 300)      av = loadf(word_embed, rowS[m] + gk, f32);
            else if (gk < 350) av = loadf(mask_embed, rowM[m] + gk - 300, f32);
            As[kk * LDT + m] = av;
            int j = nBase + m;
            float bv = 0.f;
            if (gk < 350) bv = loadf(w_ih, (long)j * 350 + gk, f32);
            Bs[kk * LDT + m] = bv;
        }
        __syncthreads();
#pragma unroll
        for (int kk = 0; kk < BK; ++kk) {
            float4 a4 = *(const float4*)&As[kk * LDT + ty * 4];
            float4 b4 = *(const float4*)&Bs[kk * LDT + tx * 4];
            float a[4] = {a4.x, a4.y, a4.z, a4.w};
            float b[4] = {b4.x, b4.y, b4.z, b4.w};
#pragma unroll
            for (int r = 0; r < 4; ++r)
#pragma unroll
                for (int c = 0; c < 4; ++c)
                    acc[r][c] = fmaf(a[r], b[c], acc[r][c]);
        }
        __syncthreads();
    }

    int j0 = nBase + tx * 4;
    float bias0 = loadf(b_ih, j0 + 0, f32) + loadf(b_hh, j0 + 0, f32);
    float bias1 = loadf(b_ih, j0 + 1, f32) + loadf(b_hh, j0 + 1, f32);
    float bias2 = loadf(b_ih, j0 + 2, f32) + loadf(b_hh, j0 + 2, f32);
    float bias3 = loadf(b_ih, j0 + 3, f32) + loadf(b_hh, j0 + 3, f32);
#pragma unroll
    for (int r = 0; r < 4; ++r) {
        int i = mBase + ty * 4 + r;
        ushort4 o;
        o.x = f2bf(acc[r][0] + bias0);
        o.y = f2bf(acc[r][1] + bias1);
        o.z = f2bf(acc[r][2] + bias2);
        o.w = f2bf(acc[r][3] + bias3);
        *(ushort4*)(xs + (long)i * 512 + j0) = o;
    }
}

// ---------------------------------------------------------------------------
// Kernel 2: LSTM recurrence for ONE direction. One block per batch elem.
// Thread t owns w_hh rows t and t+256 in fp32 registers. h lives in LDS.
// Writes h (bf16) into context[b, pos, dir*128 + d]; zero-fills invalid pos.
// ---------------------------------------------------------------------------
__global__ __launch_bounds__(256, 1) void lstm_kernel(
    const u16* __restrict__ xs,
    const void* __restrict__ w_hh,
    const int* __restrict__ lens,
    const int* __restrict__ flag,
    u16* __restrict__ context, int dir)
{
    int f32 = *flag;
    int b = blockIdx.x;
    int tid = threadIdx.x;
    int len = lens[b];

    __shared__ __align__(16) float h_s[HDq];
    __shared__ float g_s[G4];

    // zero-fill invalid positions (t >= len) for this dir's half of context
    for (int idx = tid; idx < (Lq - len) * HDq; idx += 256) {
        int p = len + (idx >> 7);
        int d = idx & 127;
        context[((b << 8) + p) * Hq + dir * HDq + d] = 0;
    }

    // load this thread's two weight rows into fp32 registers
    float4 wA[32], wB[32];
    if (f32) {
        const float4* wrA = (const float4*)((const float*)w_hh + tid * HDq);
        const float4* wrB = (const float4*)((const float*)w_hh + (tid + 256) * HDq);
#pragma unroll
        for (int j = 0; j < 32; ++j) { wA[j] = wrA[j]; wB[j] = wrB[j]; }
    } else {
        const uint4* wrA = (const uint4*)((const u16*)w_hh + tid * HDq);
        const uint4* wrB = (const uint4*)((const u16*)w_hh + (tid + 256) * HDq);
#pragma unroll
        for (int c2 = 0; c2 < 16; ++c2) {
            uint4 ra = wrA[c2];
            wA[2 * c2]     = make_float4(bflo(ra.x), bfhi(ra.x), bflo(ra.y), bfhi(ra.y));
            wA[2 * c2 + 1] = make_float4(bflo(ra.z), bfhi(ra.z), bflo(ra.w), bfhi(ra.w));
            uint4 rb = wrB[c2];
            wB[2 * c2]     = make_float4(bflo(rb.x), bfhi(rb.x), bflo(rb.y), bfhi(rb.y));
            wB[2 * c2 + 1] = make_float4(bflo(rb.z), bfhi(rb.z), bflo(rb.w), bfhi(rb.w));
        }
    }

    if (tid < HDq) h_s[tid] = 0.f;
    float c_reg = 0.f;
    __syncthreads();

    // prime xs for t=0 (xs is internal bf16)
    float cur0 = 0.f, cur1 = 0.f;
    if (len > 0) {
        int pos0 = dir ? (len - 1) : 0;
        long base = ((long)(b << 8) + pos0) * G4;
        cur0 = bf2f(xs[base + tid]);
        cur1 = bf2f(xs[base + tid + 256]);
    }

    const float4* hv = (const float4*)h_s;
    for (int t = 0; t < len; ++t) {
        int pos = dir ? (len - 1 - t) : t;
        // prefetch next step's xs
        float nx0 = 0.f, nx1 = 0.f;
        if (t + 1 < len) {
            int pos1 = dir ? (len - 2 - t) : (t + 1);
            long base1 = ((long)(b << 8) + pos1) * G4;
            nx0 = bf2f(xs[base1 + tid]);
            nx1 = bf2f(xs[base1 + tid + 256]);
        }
        // gate pre-activations: two 128-dot products (8 independent chains)
        float ax = 0.f, ay = 0.f, az = 0.f, aw = 0.f;
        float bx = 0.f, by = 0.f, bz = 0.f, bw = 0.f;
#pragma unroll
        for (int c2 = 0; c2 < 32; ++c2) {
            float4 h4 = hv[c2];
            float4 wa = wA[c2], wb = wB[c2];
            ax = fmaf(wa.x, h4.x, ax); ay = fmaf(wa.y, h4.y, ay);
            az = fmaf(wa.z, h4.z, az); aw = fmaf(wa.w, h4.w, aw);
            bx = fmaf(wb.x, h4.x, bx); by = fmaf(wb.y, h4.y, by);
            bz = fmaf(wb.z, h4.z, bz); bw = fmaf(wb.w, h4.w, bw);
        }
        g_s[tid]       = (ax + ay) + (az + aw) + cur0;
        g_s[tid + 256] = (bx + by) + (bz + bw) + cur1;
        __syncthreads();
        if (tid < HDq) {
            float gi = g_s[tid];
            float gf = g_s[HDq + tid];
            float gg = g_s[2 * HDq + tid];
            float go = g_s[3 * HDq + tid];
            float i_ = sigm(gi), f_ = sigm(gf), g_ = tanh_(gg), o_ = sigm(go);
            c_reg = f_ * c_reg + i_ * g_;
            float h = o_ * tanh_(c_reg);
            h_s[tid] = h;
            context[((b << 8) + pos) * Hq + dir * HDq + tid] = f2bf(h);
        }
        __syncthreads();
        cur0 = nx0; cur1 = nx1;
    }
}

// ---------------------------------------------------------------------------
// Kernel 3: tavg[b,h] = sum_l masks[b,l]*context[b,l,h] / sum_l masks[b,l]
// ---------------------------------------------------------------------------
__global__ void tavg_kernel(const int* __restrict__ masks,
                            const u16* __restrict__ context,
                            float* __restrict__ tavg)
{
    int b = blockIdx.x, h = threadIdx.x;
    float s = 0.f, msum = 0.f;
    for (int l = 0; l < Lq; ++l) {
        int m = masks[(b << 8) + l];
        if (m) {
            s += (float)m * bf2f(context[(((b << 8) + l) << 8) + h]);
            msum += (float)m;
        }
    }
    tavg[(b << 8) + h] = s / msum;
}

// ---------------------------------------------------------------------------
// Kernel 4: emit[i,t] = dot(context[i,:]+tavg[b,:], f2t_w[t,:]) + f2t_b[t]
// One wave (64 threads) per row i; each thread handles 4 dims.
// ---------------------------------------------------------------------------
__global__ void emit_kernel(const u16* __restrict__ context,
                            const float* __restrict__ tavg,
                            const void* __restrict__ f2t_w,
                            const void* __restrict__ f2t_b,
                            const int* __restrict__ flag,
                            float* __restrict__ emit)
{
    int f32 = *flag;
    int i = blockIdx.x;
    int b = i >> 8;
    int k = threadIdx.x;  // 0..63
    ushort4 c4 = *(const ushort4*)(context + (long)i * Hq + 4 * k);
    float4 t4 = *(const float4*)(tavg + b * Hq + 4 * k);
    float v0 = bf2f(c4.x) + t4.x, v1 = bf2f(c4.y) + t4.y;
    float v2 = bf2f(c4.z) + t4.z, v3 = bf2f(c4.w) + t4.w;
    int d = 4 * k;
    float p0 = v0 * loadf(f2t_w, d, f32) + v1 * loadf(f2t_w, d + 1, f32) +
               v2 * loadf(f2t_w, d + 2, f32) + v3 * loadf(f2t_w, d + 3, f32);
    float p1 = v0 * loadf(f2t_w, Hq + d, f32) + v1 * loadf(f2t_w, Hq + d + 1, f32) +
               v2 * loadf(f2t_w, Hq + d + 2, f32) + v3 * loadf(f2t_w, Hq + d + 3, f32);
#pragma unroll
    for (int off = 32; off >= 1; off >>= 1) {
        p0 += __shfl_down(p0, off);
        p1 += __shfl_down(p1, off);
    }
    if (k == 0) {
        emit[i * 2 + 0] = p0 + loadf(f2t_b, 0, f32);
        emit[i * 2 + 1] = p1 + loadf(f2t_b, 1, f32);
    }
}

// ---------------------------------------------------------------------------
// Kernel 5: CRF forward-backward per batch element (1 block, 64 lanes).
// ---------------------------------------------------------------------------
__global__ void crf_kernel(const float* __restrict__ emit,
                           const int* __restrict__ lens,
                           const void* __restrict__ trans,
                           const int* __restrict__ flag,
                           float* __restrict__ alphas, float* __restrict__ sp,
                           float* __restrict__ spsum)
{
    int f32 = *flag;
    int b = threadIdx.x;
    float t00 = loadf(trans, 0, f32), t01 = loadf(trans, 1, f32);
    float t10 = loadf(trans, 2, f32), t11 = loadf(trans, 3, f32);
    int len = lens[b];
    const float* eb = emit + ((long)(b << 8)) * 2;
    float* ab = alphas + ((long)(b << 8)) * 2;

    float a0 = eb[0], a1 = eb[1];
    ab[0] = a0; ab[1] = a1;
    for (int t = 1; t < Lq; ++t) {
        if (t < len) {
            float e0 = eb[2 * t], e1 = eb[2 * t + 1];
            float n0 = e0 + lse2(a0 + t00, a1 + t10);
            float n1 = e1 + lse2(a0 + t01, a1 + t11);
            a0 = n0; a1 = n1;
        }
        ab[2 * t] = a0; ab[2 * t + 1] = a1;
    }
    float logZ = lse2(a0, a1);

    float b0 = 0.f, b1 = 0.f;
    float ssum = 0.f;
    {   // position L-1
        float v = (Lq - 1 < len) ? expf(ab[2 * (Lq - 1) + 1] - logZ) : 0.f;
        sp[(b << 8) + Lq - 1] = v; ssum += v;
    }
    for (int t = Lq - 1; t >= 1; --t) {
        if (t < len) {
            float e0 = eb[2 * t], e1 = eb[2 * t + 1];
            float n0 = lse2(t00 + e0 + b0, t01 + e1 + b1);
            float n1 = lse2(t10 + e0 + b0, t11 + e1 + b1);
            b0 = n0; b1 = n1;
        }
        float v = ((t - 1) < len) ? expf(ab[2 * (t - 1) + 1] + b1 - logZ) : 0.f;
        sp[(b << 8) + t - 1] = v; ssum += v;
    }
    spsum[b] = ssum;
}

// ---------------------------------------------------------------------------
// Kernel 6: sent_v[b,h] = sum_l sp[b,l]*context[b,l,h] + spsum[b]*tavg[b,h]
// ---------------------------------------------------------------------------
__global__ void sentv_kernel(const float* __restrict__ sp,
                             const u16* __restrict__ context,
                             const float* __restrict__ tavg,
                             const float* __restrict__ spsum,
                             float* __restrict__ sentv)
{
    int b = blockIdx.x, h = threadIdx.x;
    float s = 0.f;
    for (int l = 0; l < Lq; ++l)
        s += sp[(b << 8) + l] * bf2f(context[(((b << 8) + l) << 8) + h]);
    sentv[(b << 8) + h] = s + spsum[b] * tavg[(b << 8) + h];
}

// ---------------------------------------------------------------------------
// Kernel 7: label scores + log-softmax loss + penalties -> 2 outputs
// (written as f32 or bf16 per detected dtype)
// ---------------------------------------------------------------------------
__global__ void final_kernel(const float* __restrict__ sentv,
                             const float* __restrict__ spsum,
                             const void* __restrict__ f2l_w,
                             const void* __restrict__ f2l_b,
                             const void* __restrict__ trans,
                             const int* __restrict__ labels,
                             const int* __restrict__ flag,
                             void* __restrict__ out)
{
    int f32 = *flag;
    int b = threadIdx.x;  // 64 lanes
    float s0 = 0.f, s1 = 0.f, s2 = 0.f;
    for (int h = 0; h < Hq; ++h) {
        float v = sentv[(b << 8) + h];
        s0 += v * loadf(f2l_w, h, f32);
        s1 += v * loadf(f2l_w, Hq + h, f32);
        s2 += v * loadf(f2l_w, 2 * Hq + h, f32);
    }
    s0 += loadf(f2l_b, 0, f32); s1 += loadf(f2l_b, 1, f32); s2 += loadf(f2l_b, 2, f32);
    float m = fmaxf(s0, fmaxf(s1, s2));
    float lse = m + logf(expf(s0 - m) + expf(s1 - m) + expf(s2 - m));
    int lab = labels[b];
    float sc = lab == 0 ? s0 : (lab == 1 ? s1 : s2);
    float loss = lse - sc;
    float sn = spsum[b];
#pragma unroll
    for (int off = 32; off >= 1; off >>= 1) {
        loss += __shfl_down(loss, off);
        sn += __shfl_down(sn, off);
    }
    if (b == 0) {
        float cls = loss / 64.f;
        float t00 = loadf(trans, 0, f32), t01 = loadf(trans, 1, f32);
        float t10 = loadf(trans, 2, f32), t11 = loadf(trans, 3, f32);
        float pena = fmaxf(t10 - t00, 0.f) + fmaxf(t01 - t11, 0.f);
        float np = 1.0f * pena + 0.1f * (sn / 64.f);
        if (f32) {
            ((float*)out)[0] = cls;
            ((float*)out)[1] = np;
        } else {
            ((__hip_bfloat16*)out)[0] = __float2bfloat16(cls);
            ((__hip_bfloat16*)out)[1] = __float2bfloat16(np);
        }
    }
}

extern "C" void kernel_launch(void* const* d_in, const int* in_sizes, int n_in,
                              void* d_out, int out_size, void* d_ws, size_t ws_size,
                              hipStream_t stream)
{
    const int* sents  = (const int*)d_in[0];
    const int* masks  = (const int*)d_in[1];
    const int* labels = (const int*)d_in[2];
    const int* lens   = (const int*)d_in[3];
    const void* word_embed = d_in[4];
    const void* mask_embed = d_in[5];
    const void* w_ih_f = d_in[6];
    const void* w_hh_f = d_in[7];
    const void* b_ih_f = d_in[8];
    const void* b_hh_f = d_in[9];
    const void* w_ih_b = d_in[10];
    const void* w_hh_b = d_in[11];
    const void* b_ih_b = d_in[12];
    const void* b_hh_b = d_in[13];
    const void* f2t_w  = d_in[14];
    const void* f2t_b  = d_in[15];
    const void* trans  = d_in[16];
    const void* f2l_w  = d_in[17];
    const void* f2l_b  = d_in[18];

    // workspace layout (~24.4 MB total)
    char* wsb = (char*)d_ws;
    u16*   xs      = (u16*)wsb;                       // 16384*512 bf16 = 16 MB
    u16*   context = (u16*)(wsb + 16777216);          // 16384*256 bf16 = 8 MB
    float* tavg    = (float*)(wsb + 25165824);        // 64*256 f32
    float* alphas  = (float*)(wsb + 25231360);        // 64*256*2 f32
    float* emit    = (float*)(wsb + 25362432);        // 16384*2 f32
    float* sp      = (float*)(wsb + 25493504);        // 16384 f32
    float* spsum   = (float*)(wsb + 25559040);        // 64 f32
    float* sentv   = (float*)(wsb + 25559296);        // 64*256 f32
    int*   flag    = (int*)(wsb + 25624832);          // 1 int

    detect_kernel<<<1, 64, 0, stream>>>(word_embed, flag);

    dim3 gGemm(512 / BN, 16384 / BM);  // (8, 256)

    // forward direction
    gemm_xs_kernel<<<gGemm, 256, 0, stream>>>(
        sents, masks, word_embed, mask_embed, w_ih_f, b_ih_f, b_hh_f, flag, xs);
    lstm_kernel<<<Bq, 256, 0, stream>>>(xs, w_hh_f, lens, flag, context, 0);

    // backward direction (reuses xs buffer)
    gemm_xs_kernel<<<gGemm, 256, 0, stream>>>(
        sents, masks, word_embed, mask_embed, w_ih_b, b_ih_b, b_hh_b, flag, xs);
    lstm_kernel<<<Bq, 256, 0, stream>>>(xs, w_hh_b, lens, flag, context, 1);

    tavg_kernel<<<Bq, 256, 0, stream>>>(masks, context, tavg);

    emit_kernel<<<Bq * Lq, 64, 0, stream>>>(context, tavg, f2t_w, f2t_b, flag, emit);

    crf_kernel<<<1, 64, 0, stream>>>(emit, lens, trans, flag, alphas, sp, spsum);

    sentv_kernel<<<Bq, 256, 0, stream>>>(sp, context, tavg, spsum, sentv);

    final_kernel<<<1, 64, 0, stream>>>(sentv, spsum, f2l_w, f2l_b, trans, labels,
                                       flag, d_out);
}

// Round 5
// 1031.515 us; speedup vs baseline: 1.6098x; 1.6098x over previous
//
#include <hip/hip_runtime.h>
#include <hip/hip_bf16.h>

#define Bq 64
#define Lq 256
#define Dq 350
#define HDq 128
#define Hq 256
#define G4 512   // 4*HD

typedef unsigned short u16;
typedef unsigned int u32;

__device__ __forceinline__ float bf2f(u16 u) {
    return __uint_as_float(((u32)u) << 16);
}
__device__ __forceinline__ u16 f2bf(float f) {
    __hip_bfloat16 h = __float2bfloat16(f);
    return *(u16*)&h;
}
__device__ __forceinline__ float bflo(u32 u) {
    return __uint_as_float(u << 16);
}
__device__ __forceinline__ float bfhi(u32 u) {
    return __uint_as_float(u & 0xffff0000u);
}
// dtype-polymorphic float load: f32=1 -> buffer is f32, f32=0 -> bf16
__device__ __forceinline__ float loadf(const void* p, long i, int f32) {
    return f32 ? ((const float*)p)[i] : bf2f(((const u16*)p)[i]);
}
// extract bf16 element i (0..7) from a uint4 (compile-time i folds to regs)
__device__ __forceinline__ float pick8(uint4 q, int i) {
    u32 w = (i >> 1) == 0 ? q.x : (i >> 1) == 1 ? q.y : (i >> 1) == 2 ? q.z : q.w;
    return (i & 1) ? bfhi(w) : bflo(w);
}
__device__ __forceinline__ float sigm(float x) {
    x = fminf(fmaxf(x, -30.f), 30.f);
    return 1.f / (1.f + __expf(-x));
}
__device__ __forceinline__ float tanh_(float x) {
    x = fminf(fmaxf(x, -15.f), 15.f);
    float e = __expf(2.f * x);
    return (e - 1.f) / (e + 1.f);
}
__device__ __forceinline__ float lse2(float x, float y) {
    float m = fmaxf(x, y);
    return m + logf(expf(x - m) + expf(y - m));
}

// ---------------------------------------------------------------------------
// Kernel 0: dtype detector (unchanged from R4 — proven). flag=1 => f32 bufs.
// ---------------------------------------------------------------------------
__global__ void detect_kernel(const void* we, int* flag) {
    if (threadIdx.x == 0 && blockIdx.x == 0) {
        const u16* p = (const u16*)we;
        int big = 0;
        for (int i = 0; i < 256; ++i) {
            float a = fabsf(bf2f(p[i]));
            if (!(a < 2.f)) big++;   // counts NaN too
        }
        *flag = (big > 16) ? 1 : 0;
    }
}

// ---------------------------------------------------------------------------
// Kernel 1: fused embedding-gather + input GEMM, writing TRANSPOSED xs:
//   xsT[dirRel][b][dim][s] (bf16), s = step index (dir1: s = len-1-pos).
// Covers ndir dirs starting at dirBase; grid.x = ndir*8, grid.y = 256.
// ---------------------------------------------------------------------------
#define BM 64
#define BN 64
#define BK 32
#define LDT 68  // padded LDS row stride (floats)

__global__ __launch_bounds__(256) void gemm_xs_kernel(
    const int* __restrict__ sents, const int* __restrict__ masks,
    const int* __restrict__ lens,
    const void* __restrict__ word_embed,
    const void* __restrict__ mask_embed,
    const void* __restrict__ w_ih_f, const void* __restrict__ w_ih_b,
    const void* __restrict__ b_ih_f, const void* __restrict__ b_hh_f,
    const void* __restrict__ b_ih_b, const void* __restrict__ b_hh_b,
    const int* __restrict__ flag,
    u16* __restrict__ xsT, int dirBase)
{
    __shared__ __align__(16) float As[BK * LDT];
    __shared__ __align__(16) float Bs[BK * LDT];
    __shared__ int rowS[BM];
    __shared__ int rowM[BM];

    int f32 = *flag;
    int tid = threadIdx.x;
    int mBase = blockIdx.y * BM;
    int jGlob = dirBase * 512 + blockIdx.x * BN;  // global j in [0,1024)
    int dir = jGlob >> 9;          // absolute direction of this block
    int dirRel = dir - dirBase;    // index into xsT
    int jj = jGlob & 511;          // gate-dim base (block stays in one dir)
    const void* w_ih = dir ? w_ih_b : w_ih_f;
    const void* b_ih = dir ? b_ih_b : b_ih_f;
    const void* b_hh = dir ? b_hh_b : b_hh_f;

    int b = mBase >> 8;
    int posBase = mBase & 255;
    int len = lens[b];

    if (tid < BM) {
        int i = mBase + tid;
        rowS[tid] = sents[i] * 300;
        rowM[tid] = masks[i] * 50;
    }
    int ty = tid >> 4, tx = tid & 15;
    float acc[4][4] = {};
    __syncthreads();

    for (int kt = 0; kt < 11; ++kt) {
        int k0 = kt * BK;
#pragma unroll
        for (int e = 0; e < 8; ++e) {
            int idx = e * 256 + tid;
            int m = idx >> 5, kk = idx & 31;
            int gk = k0 + kk;
            float av = 0.f;
            if (gk < 300)      av = loadf(word_embed, rowS[m] + gk, f32);
            else if (gk < 350) av = loadf(mask_embed, rowM[m] + gk - 300, f32);
            As[kk * LDT + m] = av;
            float bv = 0.f;
            if (gk < 350) bv = loadf(w_ih, (long)(jj + m) * 350 + gk, f32);
            Bs[kk * LDT + m] = bv;
        }
        __syncthreads();
#pragma unroll
        for (int kk = 0; kk < BK; ++kk) {
            float4 a4 = *(const float4*)&As[kk * LDT + ty * 4];
            float4 b4 = *(const float4*)&Bs[kk * LDT + tx * 4];
            float a[4] = {a4.x, a4.y, a4.z, a4.w};
            float bb[4] = {b4.x, b4.y, b4.z, b4.w};
#pragma unroll
            for (int r = 0; r < 4; ++r)
#pragma unroll
                for (int c = 0; c < 4; ++c)
                    acc[r][c] = fmaf(a[r], bb[c], acc[r][c]);
        }
        __syncthreads();
    }

    int dim = jj + tx * 4;
    float bias[4];
#pragma unroll
    for (int c = 0; c < 4; ++c)
        bias[c] = loadf(b_ih, dim + c, f32) + loadf(b_hh, dim + c, f32);

    // transposed scatter: xsT[(((dirRel*64+b)*512 + dim+c)*256) + s]
    long rowBase = ((long)(dirRel * 64 + b) * 512 + dim) * 256;
#pragma unroll
    for (int r = 0; r < 4; ++r) {
        int pos = posBase + ty * 4 + r;
        int s = dir ? (len - 1 - pos) : pos;
        if (s >= 0) {
#pragma unroll
            for (int c = 0; c < 4; ++c)
                xsT[rowBase + (long)c * 256 + s] = f2bf(acc[r][c] + bias[c]);
        }
    }
}

// ---------------------------------------------------------------------------
// Kernel 2: LSTM recurrence, ndir*64 blocks x 512 threads. Thread t owns
// gate row t of w_hh (128 fp32 regs). NO global ops inside the step loop:
// xs chunk-loaded (8 steps / dwordx4), h history in LDS, flushed per 128.
// ---------------------------------------------------------------------------
__global__ __launch_bounds__(512, 1) void lstm_kernel(
    const u16* __restrict__ xsT,
    const void* __restrict__ w_hh_f, const void* __restrict__ w_hh_b,
    const int* __restrict__ lens,
    const int* __restrict__ flag,
    u16* __restrict__ context, int dirBase)
{
    int f32 = *flag;
    int dirRel = blockIdx.x >> 6;
    int dir = dirBase + dirRel;
    int b = blockIdx.x & 63;
    int tid = threadIdx.x;
    int len = lens[b];
    const void* w_hh = dir ? w_hh_b : w_hh_f;

    __shared__ __align__(16) float h_s[HDq];
    __shared__ float g_s[G4];
    __shared__ __align__(16) u16 hist[128 * HDq];   // 32 KB: 128 steps of h

    // zero-fill invalid positions (pos >= len) for this dir's half
    for (int idx = tid; idx < (Lq - len) * HDq; idx += 512) {
        int p = len + (idx >> 7);
        int d = idx & 127;
        context[((b << 8) + p) * Hq + dir * HDq + d] = 0;
    }

    // this thread's weight row (gate row tid) into fp32 registers
    float4 wR[32];
    if (f32) {
        const float4* wr = (const float4*)((const float*)w_hh + (long)tid * HDq);
#pragma unroll
        for (int j = 0; j < 32; ++j) wR[j] = wr[j];
    } else {
        const uint4* wr = (const uint4*)((const u16*)w_hh + (long)tid * HDq);
#pragma unroll
        for (int c2 = 0; c2 < 16; ++c2) {
            uint4 ra = wr[c2];
            wR[2 * c2]     = make_float4(bflo(ra.x), bfhi(ra.x), bflo(ra.y), bfhi(ra.y));
            wR[2 * c2 + 1] = make_float4(bflo(ra.z), bfhi(ra.z), bflo(ra.w), bfhi(ra.w));
        }
    }

    if (tid < HDq) h_s[tid] = 0.f;
    float c_reg = 0.f;
    __syncthreads();

    const u16* xrow = xsT + ((long)(dirRel * 64 + b) * 512 + tid) * 256;
    const float4* hv = (const float4*)h_s;

    for (int seg = 0; seg < len; seg += 128) {
        int segEnd = min(seg + 128, len);
        for (int tc = seg; tc < segEnd; tc += 8) {
            uint4 q = *(const uint4*)(xrow + tc);   // 8 steps of this gate dim
#pragma unroll
            for (int u = 0; u < 8; ++u) {
                int t = tc + u;
                if (t >= segEnd) break;             // uniform: len is block-wide
                float xv = pick8(q, u);
                float a0 = 0.f, a1 = 0.f, a2 = 0.f, a3 = 0.f;
#pragma unroll
                for (int c2 = 0; c2 < 32; ++c2) {
                    float4 h4 = hv[c2];
                    float4 w4 = wR[c2];
                    a0 = fmaf(w4.x, h4.x, a0);
                    a1 = fmaf(w4.y, h4.y, a1);
                    a2 = fmaf(w4.z, h4.z, a2);
                    a3 = fmaf(w4.w, h4.w, a3);
                }
                g_s[tid] = (a0 + a1) + (a2 + a3) + xv;
                __syncthreads();
                if (tid < HDq) {
                    float gi = g_s[tid];
                    float gf = g_s[HDq + tid];
                    float gg = g_s[2 * HDq + tid];
                    float go = g_s[3 * HDq + tid];
                    float i_ = sigm(gi), f_ = sigm(gf), g_ = tanh_(gg), o_ = sigm(go);
                    c_reg = f_ * c_reg + i_ * g_;
                    float h = o_ * tanh_(c_reg);
                    h_s[tid] = h;
                    hist[(t - seg) * HDq + tid] = f2bf(h);
                }
                __syncthreads();
            }
        }
        // flush this segment's h history to context (only global ops)
        int segLen = segEnd - seg;
        for (int idx = tid; idx < segLen * 64; idx += 512) {
            int sl = idx >> 6;              // local step
            int d2 = (idx & 63) << 1;       // even dim
            int s = seg + sl;
            int pos = dir ? (len - 1 - s) : s;
            u32 v = ((const u32*)hist)[(sl << 6) + (idx & 63)];
            *(u32*)(context + ((b << 8) + pos) * Hq + dir * HDq + d2) = v;
        }
        __syncthreads();
    }
}

// ---------------------------------------------------------------------------
// Kernel 3: tavg (unchanged from R4)
// ---------------------------------------------------------------------------
__global__ void tavg_kernel(const int* __restrict__ masks,
                            const u16* __restrict__ context,
                            float* __restrict__ tavg)
{
    int b = blockIdx.x, h = threadIdx.x;
    float s = 0.f, msum = 0.f;
    for (int l = 0; l < Lq; ++l) {
        int m = masks[(b << 8) + l];
        if (m) {
            s += (float)m * bf2f(context[(((b << 8) + l) << 8) + h]);
            msum += (float)m;
        }
    }
    tavg[(b << 8) + h] = s / msum;
}

// ---------------------------------------------------------------------------
// Kernel 4: emit (unchanged from R4)
// ---------------------------------------------------------------------------
__global__ void emit_kernel(const u16* __restrict__ context,
                            const float* __restrict__ tavg,
                            const void* __restrict__ f2t_w,
                            const void* __restrict__ f2t_b,
                            const int* __restrict__ flag,
                            float* __restrict__ emit)
{
    int f32 = *flag;
    int i = blockIdx.x;
    int b = i >> 8;
    int k = threadIdx.x;  // 0..63
    ushort4 c4 = *(const ushort4*)(context + (long)i * Hq + 4 * k);
    float4 t4 = *(const float4*)(tavg + b * Hq + 4 * k);
    float v0 = bf2f(c4.x) + t4.x, v1 = bf2f(c4.y) + t4.y;
    float v2 = bf2f(c4.z) + t4.z, v3 = bf2f(c4.w) + t4.w;
    int d = 4 * k;
    float p0 = v0 * loadf(f2t_w, d, f32) + v1 * loadf(f2t_w, d + 1, f32) +
               v2 * loadf(f2t_w, d + 2, f32) + v3 * loadf(f2t_w, d + 3, f32);
    float p1 = v0 * loadf(f2t_w, Hq + d, f32) + v1 * loadf(f2t_w, Hq + d + 1, f32) +
               v2 * loadf(f2t_w, Hq + d + 2, f32) + v3 * loadf(f2t_w, Hq + d + 3, f32);
#pragma unroll
    for (int off = 32; off >= 1; off >>= 1) {
        p0 += __shfl_down(p0, off);
        p1 += __shfl_down(p1, off);
    }
    if (k == 0) {
        emit[i * 2 + 0] = p0 + loadf(f2t_b, 0, f32);
        emit[i * 2 + 1] = p1 + loadf(f2t_b, 1, f32);
    }
}

// ---------------------------------------------------------------------------
// Kernel 5: CRF forward-backward (unchanged from R4)
// ---------------------------------------------------------------------------
__global__ void crf_kernel(const float* __restrict__ emit,
                           const int* __restrict__ lens,
                           const void* __restrict__ trans,
                           const int* __restrict__ flag,
                           float* __restrict__ alphas, float* __restrict__ sp,
                           float* __restrict__ spsum)
{
    int f32 = *flag;
    int b = threadIdx.x;
    float t00 = loadf(trans, 0, f32), t01 = loadf(trans, 1, f32);
    float t10 = loadf(trans, 2, f32), t11 = loadf(trans, 3, f32);
    int len = lens[b];
    const float* eb = emit + ((long)(b << 8)) * 2;
    float* ab = alphas + ((long)(b << 8)) * 2;

    float a0 = eb[0], a1 = eb[1];
    ab[0] = a0; ab[1] = a1;
    for (int t = 1; t < Lq; ++t) {
        if (t < len) {
            float e0 = eb[2 * t], e1 = eb[2 * t + 1];
            float n0 = e0 + lse2(a0 + t00, a1 + t10);
            float n1 = e1 + lse2(a0 + t01, a1 + t11);
            a0 = n0; a1 = n1;
        }
        ab[2 * t] = a0; ab[2 * t + 1] = a1;
    }
    float logZ = lse2(a0, a1);

    float b0 = 0.f, b1 = 0.f;
    float ssum = 0.f;
    {
        float v = (Lq - 1 < len) ? expf(ab[2 * (Lq - 1) + 1] - logZ) : 0.f;
        sp[(b << 8) + Lq - 1] = v; ssum += v;
    }
    for (int t = Lq - 1; t >= 1; --t) {
        if (t < len) {
            float e0 = eb[2 * t], e1 = eb[2 * t + 1];
            float n0 = lse2(t00 + e0 + b0, t01 + e1 + b1);
            float n1 = lse2(t10 + e0 + b0, t11 + e1 + b1);
            b0 = n0; b1 = n1;
        }
        float v = ((t - 1) < len) ? expf(ab[2 * (t - 1) + 1] + b1 - logZ) : 0.f;
        sp[(b << 8) + t - 1] = v; ssum += v;
    }
    spsum[b] = ssum;
}

// ---------------------------------------------------------------------------
// Kernel 6: sentv (unchanged from R4)
// ---------------------------------------------------------------------------
__global__ void sentv_kernel(const float* __restrict__ sp,
                             const u16* __restrict__ context,
                             const float* __restrict__ tavg,
                             const float* __restrict__ spsum,
                             float* __restrict__ sentv)
{
    int b = blockIdx.x, h = threadIdx.x;
    float s = 0.f;
    for (int l = 0; l < Lq; ++l)
        s += sp[(b << 8) + l] * bf2f(context[(((b << 8) + l) << 8) + h]);
    sentv[(b << 8) + h] = s + spsum[b] * tavg[(b << 8) + h];
}

// ---------------------------------------------------------------------------
// Kernel 7: final loss (unchanged from R4)
// ---------------------------------------------------------------------------
__global__ void final_kernel(const float* __restrict__ sentv,
                             const float* __restrict__ spsum,
                             const void* __restrict__ f2l_w,
                             const void* __restrict__ f2l_b,
                             const void* __restrict__ trans,
                             const int* __restrict__ labels,
                             const int* __restrict__ flag,
                             void* __restrict__ out)
{
    int f32 = *flag;
    int b = threadIdx.x;  // 64 lanes
    float s0 = 0.f, s1 = 0.f, s2 = 0.f;
    for (int h = 0; h < Hq; ++h) {
        float v = sentv[(b << 8) + h];
        s0 += v * loadf(f2l_w, h, f32);
        s1 += v * loadf(f2l_w, Hq + h, f32);
        s2 += v * loadf(f2l_w, 2 * Hq + h, f32);
    }
    s0 += loadf(f2l_b, 0, f32); s1 += loadf(f2l_b, 1, f32); s2 += loadf(f2l_b, 2, f32);
    float m = fmaxf(s0, fmaxf(s1, s2));
    float lse = m + logf(expf(s0 - m) + expf(s1 - m) + expf(s2 - m));
    int lab = labels[b];
    float sc = lab == 0 ? s0 : (lab == 1 ? s1 : s2);
    float loss = lse - sc;
    float sn = spsum[b];
#pragma unroll
    for (int off = 32; off >= 1; off >>= 1) {
        loss += __shfl_down(loss, off);
        sn += __shfl_down(sn, off);
    }
    if (b == 0) {
        float cls = loss / 64.f;
        float t00 = loadf(trans, 0, f32), t01 = loadf(trans, 1, f32);
        float t10 = loadf(trans, 2, f32), t11 = loadf(trans, 3, f32);
        float pena = fmaxf(t10 - t00, 0.f) + fmaxf(t01 - t11, 0.f);
        float np = 1.0f * pena + 0.1f * (sn / 64.f);
        if (f32) {
            ((float*)out)[0] = cls;
            ((float*)out)[1] = np;
        } else {
            ((__hip_bfloat16*)out)[0] = __float2bfloat16(cls);
            ((__hip_bfloat16*)out)[1] = __float2bfloat16(np);
        }
    }
}

extern "C" void kernel_launch(void* const* d_in, const int* in_sizes, int n_in,
                              void* d_out, int out_size, void* d_ws, size_t ws_size,
                              hipStream_t stream)
{
    const int* sents  = (const int*)d_in[0];
    const int* masks  = (const int*)d_in[1];
    const int* labels = (const int*)d_in[2];
    const int* lens   = (const int*)d_in[3];
    const void* word_embed = d_in[4];
    const void* mask_embed = d_in[5];
    const void* w_ih_f = d_in[6];
    const void* w_hh_f = d_in[7];
    const void* b_ih_f = d_in[8];
    const void* b_hh_f = d_in[9];
    const void* w_ih_b = d_in[10];
    const void* w_hh_b = d_in[11];
    const void* b_ih_b = d_in[12];
    const void* b_hh_b = d_in[13];
    const void* f2t_w  = d_in[14];
    const void* f2t_b  = d_in[15];
    const void* trans  = d_in[16];
    const void* f2l_w  = d_in[17];
    const void* f2l_b  = d_in[18];

    const size_t XST_ONE = 16777216;           // one dir: 64*512*256 bf16
    const size_t CTX_B   = 8388608;            // context bf16
    const size_t SMALL   = 65536 + 131072 + 131072 + 65536 + 4096 + 65536 + 4096;
    const size_t NEED_MERGED = 2 * XST_ONE + CTX_B + SMALL;   // ~42.4 MB
    int merged = (ws_size >= NEED_MERGED) ? 1 : 0;

    char* wsb = (char*)d_ws;
    size_t off = merged ? 2 * XST_ONE : XST_ONE;
    u16*   xsT     = (u16*)wsb;
    u16*   context = (u16*)(wsb + off);      off += CTX_B;
    float* tavg    = (float*)(wsb + off);    off += 65536;
    float* alphas  = (float*)(wsb + off);    off += 131072;
    float* emit    = (float*)(wsb + off);    off += 131072;
    float* sp      = (float*)(wsb + off);    off += 65536;
    float* spsum   = (float*)(wsb + off);    off += 4096;
    float* sentv   = (float*)(wsb + off);    off += 65536;
    int*   flag    = (int*)(wsb + off);

    detect_kernel<<<1, 64, 0, stream>>>(word_embed, flag);

    if (merged) {
        gemm_xs_kernel<<<dim3(16, 256), 256, 0, stream>>>(
            sents, masks, lens, word_embed, mask_embed,
            w_ih_f, w_ih_b, b_ih_f, b_hh_f, b_ih_b, b_hh_b, flag, xsT, 0);
        lstm_kernel<<<128, 512, 0, stream>>>(
            xsT, w_hh_f, w_hh_b, lens, flag, context, 0);
    } else {
        // sequential-dir fallback (fits in ~25.6 MB, proven in R4)
        gemm_xs_kernel<<<dim3(8, 256), 256, 0, stream>>>(
            sents, masks, lens, word_embed, mask_embed,
            w_ih_f, w_ih_b, b_ih_f, b_hh_f, b_ih_b, b_hh_b, flag, xsT, 0);
        lstm_kernel<<<64, 512, 0, stream>>>(
            xsT, w_hh_f, w_hh_b, lens, flag, context, 0);
        gemm_xs_kernel<<<dim3(8, 256), 256, 0, stream>>>(
            sents, masks, lens, word_embed, mask_embed,
            w_ih_f, w_ih_b, b_ih_f, b_hh_f, b_ih_b, b_hh_b, flag, xsT, 1);
        lstm_kernel<<<64, 512, 0, stream>>>(
            xsT, w_hh_f, w_hh_b, lens, flag, context, 1);
    }

    tavg_kernel<<<Bq, 256, 0, stream>>>(masks, context, tavg);

    emit_kernel<<<Bq * Lq, 64, 0, stream>>>(context, tavg, f2t_w, f2t_b, flag, emit);

    crf_kernel<<<1, 64, 0, stream>>>(emit, lens, trans, flag, alphas, sp, spsum);

    sentv_kernel<<<Bq, 256, 0, stream>>>(sp, context, tavg, spsum, sentv);

    final_kernel<<<1, 64, 0, stream>>>(sentv, spsum, f2l_w, f2l_b, trans, labels,
                                       flag, d_out);
}